// Round 7
// baseline (1138.727 us; speedup 1.0000x reference)
//
#include <hip/hip_runtime.h>

typedef __attribute__((ext_vector_type(4))) float f32x4;
typedef __attribute__((ext_vector_type(8))) _Float16 f16x8;

#define D 256          // D_in == D_out == 256
#define VBS 128        // ghost batch rows per chunk
#define BN_EPS 1e-5f

// Pack W[k][n] (f32, row-major 256x256) into f16 MFMA fragment order.
// Used as the A-operand (A = W^T tile); frag value = W[kb*32+(l>>4)*8+j][ct*16+(l&15)].
__global__ void pack_w_kernel(const float* __restrict__ W, _Float16* __restrict__ wp) {
    int idx = blockIdx.x * blockDim.x + threadIdx.x;   // [0, 8192)
    int kb  = idx >> 10;          // 8 k-blocks of 32
    int rem = idx & 1023;
    int ct  = rem >> 6;           // 16 col-tiles of 16
    int l   = rem & 63;           // lane
    int col = ct * 16 + (l & 15);
    int k0  = kb * 32 + ((l >> 4) << 3);
    f16x8 v;
#pragma unroll
    for (int j = 0; j < 8; ++j) v[j] = (_Float16)W[(k0 + j) * D + col];
    *reinterpret_cast<f16x8*>(wp + (size_t)idx * 8) = v;
}

// 16-lane (DPP row) all-lanes sum: 4 x v_add_f32 with row_ror, VALU pipe only.
template <int CTRL>
__device__ __forceinline__ float row_ror_add(float x) {
    int v = __builtin_amdgcn_update_dpp(0, __builtin_bit_cast(int, x),
                                        CTRL, 0xF, 0xF, true);
    return x + __builtin_bit_cast(float, v);
}
__device__ __forceinline__ float rsum16(float x) {
    x = row_ror_add<0x128>(x);   // += ror 8
    x = row_ror_add<0x124>(x);   // += ror 4
    x = row_ror_add<0x122>(x);   // += ror 2
    x = row_ror_add<0x121>(x);   // += ror 1
    return x;
}

// Stage one 16 KB K-slab of packed W into LDS (linear layout, 2 issues x 8 KB).
// Dest is wave-uniform base + lane*16 (global_load_lds HW rule) == tid*16 here.
#define STAGE_W(bufp, kb)                                                              \
    do {                                                                               \
        const char* _g = (const char*)Wp + (size_t)(kb) * 16384 + (size_t)tid * 16;    \
        char* _l = (char*)(bufp) + (size_t)tid * 16;                                   \
        __builtin_amdgcn_global_load_lds(                                              \
            (const __attribute__((address_space(1))) unsigned*)_g,                     \
            (__attribute__((address_space(3))) unsigned*)_l, 16, 0, 0);                \
        __builtin_amdgcn_global_load_lds(                                              \
            (const __attribute__((address_space(1))) unsigned*)(_g + 8192),            \
            (__attribute__((address_space(3))) unsigned*)(_l + 8192), 16, 0, 0);       \
    } while (0)

// One block per BN chunk of 128 rows; 8 waves x 16 rows (one strip per wave).
// TRANSPOSED mfma: acc[ct] = mfma(W^T-frag, a-frag) -> h^T fragment:
//   lane holds row (chunk*128 + wid*16 + lane&15), cols ct*16 + (lane>>4)*4 + {0..3}.
// W K-slabs double-buffered in LDS (16 KB each) -> ds_read_b128, no L2 thrash.
__global__ __launch_bounds__(512, 4)
void fused_kernel(const float* __restrict__ A, const float* __restrict__ priors,
                  const _Float16* __restrict__ Wp, const float* __restrict__ gamma,
                  const float* __restrict__ beta, float* __restrict__ out) {
    const int tid  = threadIdx.x;
    const int wid  = tid >> 6;    // 0..7
    const int lane = tid & 63;
    const int lrow = lane & 15;   // row within the wave's 16-row strip
    const int q    = lane >> 4;   // col-quad group (0..3)

    const int myrow = blockIdx.x * VBS + wid * 16 + lrow;

    __shared__ f16x8 sW[2][1024];   // 2 x 16 KB double-buffered W K-slab
    __shared__ float sSum[8][D];    // 8 KB
    __shared__ float sSq[8][D];     // 8 KB
    __shared__ float sA[D], sB[D];  // 2 KB   (total 50 KB)

    f32x4 acc[16];
#pragma unroll
    for (int ct = 0; ct < 16; ++ct) {
        f32x4 z = {0.f, 0.f, 0.f, 0.f};
        acc[ct] = z;
    }

    const float* a0 = A + (size_t)myrow * D + q * 8;

    // ---- GEMM: h^T = W^T @ a^T, K=256 in 8 slabs of 32; W via LDS dbuf ----
    STAGE_W(&sW[0][0], 0);
    f32x4 lo = *reinterpret_cast<const f32x4*>(a0);
    f32x4 hi = *reinterpret_cast<const f32x4*>(a0 + 4);
    __syncthreads();   // vmcnt(0) drain: slab 0 staged (and a-prefetch landed)

#pragma unroll 1
    for (int kb = 0; kb < 8; ++kb) {
        if (kb < 7) STAGE_W(&sW[(kb + 1) & 1][0], kb + 1);   // async into other buffer
        f16x8 t;
#pragma unroll
        for (int j = 0; j < 4; ++j) { t[j] = (_Float16)lo[j]; t[j + 4] = (_Float16)hi[j]; }
        if (kb < 7) {   // a-prefetch for next slab, overwrites converted regs
            lo = *reinterpret_cast<const f32x4*>(a0 + (kb + 1) * 32);
            hi = *reinterpret_cast<const f32x4*>(a0 + (kb + 1) * 32 + 4);
        }
        const f16x8* wb = &sW[kb & 1][lane];   // frag (ct,lane) at ct*64+lane
#pragma unroll
        for (int g = 0; g < 4; ++g) {
            f16x8 w0 = wb[(g * 4 + 0) * 64];
            f16x8 w1 = wb[(g * 4 + 1) * 64];
            f16x8 w2 = wb[(g * 4 + 2) * 64];
            f16x8 w3 = wb[(g * 4 + 3) * 64];
            acc[g * 4 + 0] = __builtin_amdgcn_mfma_f32_16x16x32_f16(w0, t, acc[g * 4 + 0], 0, 0, 0);
            acc[g * 4 + 1] = __builtin_amdgcn_mfma_f32_16x16x32_f16(w1, t, acc[g * 4 + 1], 0, 0, 0);
            acc[g * 4 + 2] = __builtin_amdgcn_mfma_f32_16x16x32_f16(w2, t, acc[g * 4 + 2], 0, 0, 0);
            acc[g * 4 + 3] = __builtin_amdgcn_mfma_f32_16x16x32_f16(w3, t, acc[g * 4 + 3], 0, 0, 0);
        }
        __syncthreads();   // reads of sW[kb&1] done by all; stage(kb+1) drained
    }

    // ---- Ghost BN stats: per-column sum/sumsq over 128 rows (DPP, VALU-only) ----
#pragma unroll
    for (int ct = 0; ct < 16; ++ct) {
        f32x4 s = acc[ct];
        f32x4 qv = s * s;
#pragma unroll
        for (int c = 0; c < 4; ++c) { s[c] = rsum16(s[c]); qv[c] = rsum16(qv[c]); }
        if (lrow == 0) {
            *reinterpret_cast<f32x4*>(&sSum[wid][ct * 16 + q * 4]) = s;
            *reinterpret_cast<f32x4*>(&sSq [wid][ct * 16 + q * 4]) = qv;
        }
    }
    __syncthreads();

    if (tid < D) {
        float s = 0.f, qq = 0.f;
#pragma unroll
        for (int w = 0; w < 8; ++w) { s += sSum[w][tid]; qq += sSq[w][tid]; }
        float mean = s * (1.0f / 128.0f);
        float var  = qq * (1.0f / 128.0f) - mean * mean;
        float g    = gamma[tid] * rsqrtf(var + BN_EPS);
        sA[tid] = g;
        sB[tid] = beta[tid] - mean * g;
    }
    __syncthreads();

    // ---- epilogue: BN apply, * priors, sparsemax (one row per lrow-lane) ----
    const float* pr = priors + (size_t)myrow * D;
    float m = -1e30f;
#pragma unroll 4
    for (int ct = 0; ct < 16; ++ct) {
        int c0 = ct * 16 + q * 4;
        f32x4 ga = *reinterpret_cast<const f32x4*>(&sA[c0]);
        f32x4 bb = *reinterpret_cast<const f32x4*>(&sB[c0]);
        f32x4 p  = *reinterpret_cast<const f32x4*>(pr + c0);
        f32x4 x  = (acc[ct] * ga + bb) * p;
        acc[ct] = x;
        m = fmaxf(m, fmaxf(fmaxf(x[0], x[1]), fmaxf(x[2], x[3])));
    }
    m = fmaxf(m, __shfl_xor(m, 16));
    m = fmaxf(m, __shfl_xor(m, 32));

    // Michelot fixed-point, max-shift folded into tau0 = m - 1.
    float tau = m - 1.0f;
#pragma unroll 1
    for (int it = 0; it < 32; ++it) {
        float s = 0.f, c = 0.f;
#pragma unroll
        for (int ct = 0; ct < 16; ++ct) {
#pragma unroll
            for (int k = 0; k < 4; ++k) {
                float z = acc[ct][k];
                if (z > tau) { s += z; c += 1.f; }
            }
        }
        s += __shfl_xor(s, 16); c += __shfl_xor(c, 16);
        s += __shfl_xor(s, 32); c += __shfl_xor(c, 32);
        float n = (s - 1.0f) / c;
        bool done = (n <= tau);
        tau = fmaxf(tau, n);
        if (__all(done)) break;
    }

    float* ob = out + (size_t)myrow * D;
#pragma unroll
    for (int ct = 0; ct < 16; ++ct) {
        int c0 = ct * 16 + q * 4;
        f32x4 x = acc[ct];
        f32x4 r;
#pragma unroll
        for (int k = 0; k < 4; ++k) r[k] = fmaxf(x[k] - tau, 0.f);
        __builtin_nontemporal_store(r, reinterpret_cast<f32x4*>(&ob[c0]));
    }
}

extern "C" void kernel_launch(void* const* d_in, const int* in_sizes, int n_in,
                              void* d_out, int out_size, void* d_ws, size_t ws_size,
                              hipStream_t stream) {
    const float* a      = (const float*)d_in[0];
    const float* priors = (const float*)d_in[1];
    const float* W      = (const float*)d_in[2];
    // d_in[3] = b : unused — ghost-BN mean subtraction cancels any per-column bias.
    const float* gamma  = (const float*)d_in[4];
    const float* beta   = (const float*)d_in[5];
    float* out = (float*)d_out;
    _Float16* wp = (_Float16*)d_ws;   // 256*256 f16 = 128 KB packed W

    const int B = in_sizes[0] / D;        // 262144
    const int nchunks = B / VBS;          // 2048

    hipLaunchKernelGGL(pack_w_kernel, dim3(32), dim3(256), 0, stream, W, wp);
    hipLaunchKernelGGL(fused_kernel, dim3(nchunks), dim3(512), 0, stream,
                       a, priors, wp, gamma, beta, out);
}

// Round 8
// 708.630 us; speedup vs baseline: 1.6069x; 1.6069x over previous
//
#include <hip/hip_runtime.h>

typedef __attribute__((ext_vector_type(4))) float f32x4;
typedef __attribute__((ext_vector_type(8))) _Float16 f16x8;
typedef __attribute__((ext_vector_type(4))) _Float16 f16x4;

#define D 256          // D_in == D_out == 256
#define VBS 128        // ghost batch rows per chunk
#define BN_EPS 1e-5f

// ---------------------------------------------------------------- pack W
// Pack W[k][n] (f32, row-major 256x256) into f16 MFMA fragment order.
// frag value = W[kb*32+(l>>4)*8+j][ct*16+(l&15)].
__global__ void pack_w_kernel(const float* __restrict__ W, _Float16* __restrict__ wp) {
    int idx = blockIdx.x * blockDim.x + threadIdx.x;   // [0, 8192)
    int kb  = idx >> 10;
    int rem = idx & 1023;
    int ct  = rem >> 6;
    int l   = rem & 63;
    int col = ct * 16 + (l & 15);
    int k0  = kb * 32 + ((l >> 4) << 3);
    f16x8 v;
#pragma unroll
    for (int j = 0; j < 8; ++j) v[j] = (_Float16)W[(k0 + j) * D + col];
    *reinterpret_cast<f16x8*>(wp + (size_t)idx * 8) = v;
}

// 16-lane (DPP row) all-lanes sum: VALU pipe only.
template <int CTRL>
__device__ __forceinline__ float row_ror_add(float x) {
    int v = __builtin_amdgcn_update_dpp(0, __builtin_bit_cast(int, x),
                                        CTRL, 0xF, 0xF, true);
    return x + __builtin_bit_cast(float, v);
}
__device__ __forceinline__ float rsum16(float x) {
    x = row_ror_add<0x128>(x);
    x = row_ror_add<0x124>(x);
    x = row_ror_add<0x122>(x);
    x = row_ror_add<0x121>(x);
    return x;
}

// ---------------------------------------------------------------- K1: GEMM + stats
// One block per chunk; 8 waves x 16 rows. Transposed mfma (lane = row).
// Outputs: h (f16, row-major) and per-chunk BN coeffs gA/gB.
__global__ __launch_bounds__(512, 2)
void gemm_stats_kernel(const float* __restrict__ A, const _Float16* __restrict__ Wp,
                       const float* __restrict__ gamma, const float* __restrict__ beta,
                       float* __restrict__ gA, float* __restrict__ gB,
                       _Float16* __restrict__ H) {
    const int tid  = threadIdx.x;
    const int wid  = tid >> 6;
    const int lane = tid & 63;
    const int lrow = lane & 15;
    const int q    = lane >> 4;

    const int myrow = blockIdx.x * VBS + wid * 16 + lrow;

    f32x4 acc[16];
#pragma unroll
    for (int ct = 0; ct < 16; ++ct) {
        f32x4 z = {0.f, 0.f, 0.f, 0.f};
        acc[ct] = z;
    }

    const float* a0 = A + (size_t)myrow * D + q * 8;
#pragma unroll
    for (int kb = 0; kb < 8; ++kb) {
        f32x4 lo = *reinterpret_cast<const f32x4*>(a0 + kb * 32);
        f32x4 hi = *reinterpret_cast<const f32x4*>(a0 + kb * 32 + 4);
        f16x8 t;
#pragma unroll
        for (int j = 0; j < 4; ++j) { t[j] = (_Float16)lo[j]; t[j + 4] = (_Float16)hi[j]; }
        const f16x8* wpp = reinterpret_cast<const f16x8*>(Wp) + kb * 1024 + lane;
#pragma unroll
        for (int ct = 0; ct < 16; ++ct) {
            f16x8 wf = wpp[ct * 64];
            acc[ct] = __builtin_amdgcn_mfma_f32_16x16x32_f16(wf, t, acc[ct], 0, 0, 0);
        }
    }

    // stats: per-column sum/sumsq over 128 rows (DPP over 16 lanes, LDS combine)
    __shared__ float sSum[8][D];
    __shared__ float sSq[8][D];
#pragma unroll
    for (int ct = 0; ct < 16; ++ct) {
        f32x4 s = acc[ct];
        f32x4 qv = s * s;
#pragma unroll
        for (int c = 0; c < 4; ++c) { s[c] = rsum16(s[c]); qv[c] = rsum16(qv[c]); }
        if (lrow == 0) {
            *reinterpret_cast<f32x4*>(&sSum[wid][ct * 16 + q * 4]) = s;
            *reinterpret_cast<f32x4*>(&sSq [wid][ct * 16 + q * 4]) = qv;
        }
    }

    // store h as f16 while stats settle (no dependence on barrier)
    _Float16* hb = H + (size_t)myrow * D;
#pragma unroll
    for (int ct = 0; ct < 16; ++ct) {
        f16x4 hv;
#pragma unroll
        for (int k = 0; k < 4; ++k) hv[k] = (_Float16)acc[ct][k];
        *reinterpret_cast<f16x4*>(hb + ct * 16 + q * 4) = hv;
    }

    __syncthreads();
    if (tid < D) {
        float s = 0.f, qq = 0.f;
#pragma unroll
        for (int w = 0; w < 8; ++w) { s += sSum[w][tid]; qq += sSq[w][tid]; }
        float mean = s * (1.0f / 128.0f);
        float var  = qq * (1.0f / 128.0f) - mean * mean;
        float g    = gamma[tid] * rsqrtf(var + BN_EPS);
        gA[blockIdx.x * D + tid] = g;
        gB[blockIdx.x * D + tid] = beta[tid] - mean * g;
    }
}

// ---------------------------------------------------------------- K2: apply + sparsemax
// Barrier-free streaming: 4 threads per row, 64 values each; tau reduction
// over the 4-lane group (shfl_xor 1,2).
__global__ __launch_bounds__(256, 4)
void sparsemax_kernel(const _Float16* __restrict__ H, const float* __restrict__ priors,
                      const float* __restrict__ gA, const float* __restrict__ gB,
                      float* __restrict__ out) {
    const int gid = blockIdx.x * 256 + threadIdx.x;
    const int r   = gid >> 2;          // row
    const int c0  = (gid & 3) * 64;    // this thread's 64-col segment
    const int chunk = r >> 7;

    const _Float16* hp = H + (size_t)r * D + c0;
    const float* pp = priors + (size_t)r * D + c0;
    const float* ga = gA + chunk * D + c0;
    const float* gb = gB + chunk * D + c0;

    float z[64];
    float m = -1e30f;
#pragma unroll
    for (int i = 0; i < 8; ++i) {
        f16x8 hv = *reinterpret_cast<const f16x8*>(hp + i * 8);
        f32x4 p0 = *reinterpret_cast<const f32x4*>(pp + i * 8);
        f32x4 p1 = *reinterpret_cast<const f32x4*>(pp + i * 8 + 4);
        f32x4 a0 = *reinterpret_cast<const f32x4*>(ga + i * 8);
        f32x4 a1 = *reinterpret_cast<const f32x4*>(ga + i * 8 + 4);
        f32x4 b0 = *reinterpret_cast<const f32x4*>(gb + i * 8);
        f32x4 b1 = *reinterpret_cast<const f32x4*>(gb + i * 8 + 4);
#pragma unroll
        for (int j = 0; j < 4; ++j) {
            float x0 = ((float)hv[j]     * a0[j] + b0[j]) * p0[j];
            float x1 = ((float)hv[j + 4] * a1[j] + b1[j]) * p1[j];
            z[i * 8 + j]     = x0;
            z[i * 8 + j + 4] = x1;
            m = fmaxf(m, fmaxf(x0, x1));
        }
    }
    m = fmaxf(m, __shfl_xor(m, 1));
    m = fmaxf(m, __shfl_xor(m, 2));

    // Michelot fixed-point from tau0 = m-1 (monotone to exact root).
    float tau = m - 1.0f;
#pragma unroll 1
    for (int it = 0; it < 32; ++it) {
        float s = 0.f, c = 0.f;
#pragma unroll
        for (int i = 0; i < 64; ++i) {
            float zz = z[i];
            if (zz > tau) { s += zz; c += 1.f; }
        }
        s += __shfl_xor(s, 1); c += __shfl_xor(c, 1);
        s += __shfl_xor(s, 2); c += __shfl_xor(c, 2);
        float n = (s - 1.0f) / c;
        bool done = (n <= tau);
        tau = fmaxf(tau, n);
        if (__all(done)) break;
    }

    float* ob = out + (size_t)r * D + c0;
#pragma unroll
    for (int i = 0; i < 16; ++i) {
        f32x4 rv;
#pragma unroll
        for (int j = 0; j < 4; ++j) rv[j] = fmaxf(z[i * 4 + j] - tau, 0.f);
        __builtin_nontemporal_store(rv, reinterpret_cast<f32x4*>(&ob[i * 4]));
    }
}

// ---------------------------------------------------------------- fallback fused (R6)
__global__ __launch_bounds__(512, 4)
void fused_kernel(const float* __restrict__ A, const float* __restrict__ priors,
                  const _Float16* __restrict__ Wp, const float* __restrict__ gamma,
                  const float* __restrict__ beta, float* __restrict__ out) {
    const int tid  = threadIdx.x;
    const int wid  = tid >> 6;
    const int lane = tid & 63;
    const int lrow = lane & 15;
    const int q    = lane >> 4;
    const int myrow = blockIdx.x * VBS + wid * 16 + lrow;

    f32x4 acc[16];
#pragma unroll
    for (int ct = 0; ct < 16; ++ct) { f32x4 z = {0.f,0.f,0.f,0.f}; acc[ct] = z; }
    const float* a0 = A + (size_t)myrow * D + q * 8;
    f32x4 lo = *reinterpret_cast<const f32x4*>(a0);
    f32x4 hi = *reinterpret_cast<const f32x4*>(a0 + 4);
#pragma unroll 1
    for (int kb = 0; kb < 8; ++kb) {
        f16x8 t;
#pragma unroll
        for (int j = 0; j < 4; ++j) { t[j] = (_Float16)lo[j]; t[j+4] = (_Float16)hi[j]; }
        if (kb < 7) {
            lo = *reinterpret_cast<const f32x4*>(a0 + (kb+1)*32);
            hi = *reinterpret_cast<const f32x4*>(a0 + (kb+1)*32 + 4);
        }
        const f16x8* wpp = reinterpret_cast<const f16x8*>(Wp) + kb * 1024 + lane;
#pragma unroll
        for (int g = 0; g < 4; ++g) {
            f16x8 w0 = wpp[(g*4+0)*64], w1 = wpp[(g*4+1)*64];
            f16x8 w2 = wpp[(g*4+2)*64], w3 = wpp[(g*4+3)*64];
            acc[g*4+0] = __builtin_amdgcn_mfma_f32_16x16x32_f16(w0, t, acc[g*4+0], 0,0,0);
            acc[g*4+1] = __builtin_amdgcn_mfma_f32_16x16x32_f16(w1, t, acc[g*4+1], 0,0,0);
            acc[g*4+2] = __builtin_amdgcn_mfma_f32_16x16x32_f16(w2, t, acc[g*4+2], 0,0,0);
            acc[g*4+3] = __builtin_amdgcn_mfma_f32_16x16x32_f16(w3, t, acc[g*4+3], 0,0,0);
        }
    }
    __shared__ float sSum[8][D];
    __shared__ float sSq[8][D];
#pragma unroll
    for (int ct = 0; ct < 16; ++ct) {
        f32x4 s = acc[ct]; f32x4 qv = s * s;
#pragma unroll
        for (int c = 0; c < 4; ++c) { s[c] = rsum16(s[c]); qv[c] = rsum16(qv[c]); }
        if (lrow == 0) {
            *reinterpret_cast<f32x4*>(&sSum[wid][ct*16 + q*4]) = s;
            *reinterpret_cast<f32x4*>(&sSq [wid][ct*16 + q*4]) = qv;
        }
    }
    __syncthreads();
    __shared__ float sA[D], sB[D];
    if (tid < D) {
        float s = 0.f, qq = 0.f;
#pragma unroll
        for (int w = 0; w < 8; ++w) { s += sSum[w][tid]; qq += sSq[w][tid]; }
        float mean = s * (1.0f/128.0f);
        float var  = qq * (1.0f/128.0f) - mean*mean;
        float g    = gamma[tid] * rsqrtf(var + BN_EPS);
        sA[tid] = g; sB[tid] = beta[tid] - mean * g;
    }
    __syncthreads();
    const float* pr = priors + (size_t)myrow * D;
    float m = -1e30f;
#pragma unroll 4
    for (int ct = 0; ct < 16; ++ct) {
        int c0 = ct*16 + q*4;
        f32x4 ga = *reinterpret_cast<const f32x4*>(&sA[c0]);
        f32x4 bb = *reinterpret_cast<const f32x4*>(&sB[c0]);
        f32x4 p  = *reinterpret_cast<const f32x4*>(pr + c0);
        f32x4 x  = (acc[ct] * ga + bb) * p;
        acc[ct] = x;
        m = fmaxf(m, fmaxf(fmaxf(x[0], x[1]), fmaxf(x[2], x[3])));
    }
    m = fmaxf(m, __shfl_xor(m, 16));
    m = fmaxf(m, __shfl_xor(m, 32));
    float tau = m - 1.0f;
#pragma unroll 1
    for (int it = 0; it < 32; ++it) {
        float s = 0.f, c = 0.f;
#pragma unroll
        for (int ct = 0; ct < 16; ++ct)
#pragma unroll
            for (int k = 0; k < 4; ++k) {
                float zz = acc[ct][k];
                if (zz > tau) { s += zz; c += 1.f; }
            }
        s += __shfl_xor(s, 16); c += __shfl_xor(c, 16);
        s += __shfl_xor(s, 32); c += __shfl_xor(c, 32);
        float n = (s - 1.0f) / c;
        bool done = (n <= tau);
        tau = fmaxf(tau, n);
        if (__all(done)) break;
    }
    float* ob = out + (size_t)myrow * D;
#pragma unroll
    for (int ct = 0; ct < 16; ++ct) {
        int c0 = ct*16 + q*4;
        f32x4 x = acc[ct]; f32x4 r;
#pragma unroll
        for (int k = 0; k < 4; ++k) r[k] = fmaxf(x[k] - tau, 0.f);
        __builtin_nontemporal_store(r, reinterpret_cast<f32x4*>(&ob[c0]));
    }
}

extern "C" void kernel_launch(void* const* d_in, const int* in_sizes, int n_in,
                              void* d_out, int out_size, void* d_ws, size_t ws_size,
                              hipStream_t stream) {
    const float* a      = (const float*)d_in[0];
    const float* priors = (const float*)d_in[1];
    const float* W      = (const float*)d_in[2];
    // d_in[3] = b : unused — ghost-BN mean subtraction cancels any per-column bias.
    const float* gamma  = (const float*)d_in[4];
    const float* beta   = (const float*)d_in[5];
    float* out = (float*)d_out;

    const int B = in_sizes[0] / D;        // 262144
    const int nchunks = B / VBS;          // 2048

    // workspace layout
    const size_t WP_BYTES = (size_t)D * D * sizeof(_Float16);          // 128 KB
    const size_t GA_BYTES = (size_t)nchunks * D * sizeof(float);       // 2 MB
    const size_t H_BYTES  = (size_t)B * D * sizeof(_Float16);          // 128 MB
    const size_t NEEDED   = WP_BYTES + 2 * GA_BYTES + H_BYTES;

    _Float16* wp = (_Float16*)d_ws;
    hipLaunchKernelGGL(pack_w_kernel, dim3(32), dim3(256), 0, stream, W, wp);

    if (ws_size >= NEEDED) {
        float*    gA = (float*)((char*)d_ws + WP_BYTES);
        float*    gB = (float*)((char*)d_ws + WP_BYTES + GA_BYTES);
        _Float16* H  = (_Float16*)((char*)d_ws + WP_BYTES + 2 * GA_BYTES);
        hipLaunchKernelGGL(gemm_stats_kernel, dim3(nchunks), dim3(512), 0, stream,
                           a, wp, gamma, beta, gA, gB, H);
        hipLaunchKernelGGL(sparsemax_kernel, dim3(B / 64), dim3(256), 0, stream,
                           H, priors, gA, gB, out);
    } else {
        hipLaunchKernelGGL(fused_kernel, dim3(nchunks), dim3(512), 0, stream,
                           a, priors, wp, gamma, beta, out);
    }
}

// Round 9
// 218.741 us; speedup vs baseline: 5.2058x; 3.2396x over previous
//
#include <hip/hip_runtime.h>

typedef __attribute__((ext_vector_type(4))) float f32x4;
typedef __attribute__((ext_vector_type(8))) _Float16 f16x8;

#define D 256          // D_in == D_out == 256
#define VBS 128        // ghost batch rows per chunk
#define BN_EPS 1e-5f

// ---------------------------------------------------------------- pack W
// Pack W[k][n] (f32, row-major 256x256) into f16 MFMA fragment order.
// frag value = W[kb*32+(l>>4)*8+j][ct*16+(l&15)], frag (kb,ct,lane) at
// wp + ((kb*16+ct)*64+lane)*8.
__global__ void pack_w_kernel(const float* __restrict__ W, _Float16* __restrict__ wp) {
    int idx = blockIdx.x * blockDim.x + threadIdx.x;   // [0, 8192)
    int kb  = idx >> 10;
    int rem = idx & 1023;
    int ct  = rem >> 6;
    int l   = rem & 63;
    int col = ct * 16 + (l & 15);
    int k0  = kb * 32 + ((l >> 4) << 3);
    f16x8 v;
#pragma unroll
    for (int j = 0; j < 8; ++j) v[j] = (_Float16)W[(k0 + j) * D + col];
    *reinterpret_cast<f16x8*>(wp + (size_t)idx * 8) = v;
}

// 16-lane (DPP row) all-lanes sum: VALU pipe only.
template <int CTRL>
__device__ __forceinline__ float row_ror_add(float x) {
    int v = __builtin_amdgcn_update_dpp(0, __builtin_bit_cast(int, x),
                                        CTRL, 0xF, 0xF, true);
    return x + __builtin_bit_cast(float, v);
}
__device__ __forceinline__ float rsum16(float x) {
    x = row_ror_add<0x128>(x);
    x = row_ror_add<0x124>(x);
    x = row_ror_add<0x122>(x);
    x = row_ror_add<0x121>(x);
    return x;
}

#define GLL16(g, l)                                                     \
    __builtin_amdgcn_global_load_lds(                                   \
        (const __attribute__((address_space(1))) unsigned*)(g),         \
        (__attribute__((address_space(3))) unsigned*)(l), 16, 0, 0)

// Fused: one block per BN chunk (128 rows); 8 waves x 16 rows.
// TRANSPOSED mfma: acc[ct] = mfma(W^T-frag, a-frag); lane = row, cols
// ct*16 + q*4 + {0..3}. Per K-slab (K=32): W slab 16 KB + a slab 16 KB
// staged via global_load_lds (double-buffered) -> ~32 KB of reads in
// flight per block (Little's law: need ~9 KB/CU for 6.3 TB/s).
// a-slab is staged in FRAGMENT order (per-lane contiguous 32 B) by
// pre-swizzling the global source address (m173 pattern).
__global__ __launch_bounds__(512, 2)
void fused_kernel(const float* __restrict__ A, const float* __restrict__ priors,
                  const _Float16* __restrict__ Wp, const float* __restrict__ gamma,
                  const float* __restrict__ beta, float* __restrict__ out) {
    const int tid  = threadIdx.x;
    const int wid  = tid >> 6;    // 0..7
    const int lane = tid & 63;
    const int lrow = lane & 15;
    const int q    = lane >> 4;
    const int chunk = blockIdx.x;
    const int myrow = chunk * VBS + wid * 16 + lrow;

    // [0,32768): W slabs 2x16KB ; [32768,65536): a slabs 2x16KB
    // stats overlay [0,18432) after the GEMM completes.
    __shared__ char smem[65536];

    f32x4 acc[16];
#pragma unroll
    for (int ct = 0; ct < 16; ++ct) { f32x4 z = {0.f,0.f,0.f,0.f}; acc[ct] = z; }

    // --- per-thread staging addresses ---
    // W source: linear, piece tid and tid+512 (16 B pieces) of each 16 KB slab.
    const char* wsrc = (const char*)Wp + (size_t)tid * 16;
    // a source: piece t -> LDS byte t*16; slot = t>>1 (32 B frags), pc = t&1.
    //   slot -> (wid_t = slot>>6, lane_t = slot&63); frag holds
    //   a[chunk*128 + wid_t*16 + (lane_t&15)][kb*32 + (lane_t>>4)*8 + pc*4 ..+4]
    const char* asrc0;
    const char* asrc1;
    {
        int t0 = tid, t1 = tid + 512;
        int s0 = t0 >> 1, p0 = t0 & 1, s1 = t1 >> 1, p1 = t1 & 1;
        size_t f0 = (size_t)(chunk * VBS + (s0 >> 6) * 16 + ((s0 & 63) & 15)) * D
                    + ((s0 & 63) >> 4) * 8 + p0 * 4;
        size_t f1 = (size_t)(chunk * VBS + (s1 >> 6) * 16 + ((s1 & 63) & 15)) * D
                    + ((s1 & 63) >> 4) * 8 + p1 * 4;
        asrc0 = (const char*)(A + f0);
        asrc1 = (const char*)(A + f1);
    }
    char* wdst = smem + (size_t)tid * 16;
    char* adst = smem + 32768 + (size_t)tid * 16;

    // prologue: stage slab 0 (W + a), then drain.
    GLL16(wsrc,        wdst);
    GLL16(wsrc + 8192, wdst + 8192);
    GLL16(asrc0,       adst);
    GLL16(asrc1,       adst + 8192);
    __syncthreads();

    const int abase = 32768 + (wid * 64 + lane) * 32;   // my a-frag byte offset
#pragma unroll 1
    for (int kb = 0; kb < 8; ++kb) {
        const int cur = (kb & 1) * 16384;
        if (kb < 7) {   // async stage of next slab; flies during this compute
            const int nxt = ((kb + 1) & 1) * 16384;
            const char* wk = wsrc + (size_t)(kb + 1) * 16384;
            GLL16(wk,        wdst + nxt);
            GLL16(wk + 8192, wdst + nxt + 8192);
            const char* ak0 = asrc0 + (size_t)(kb + 1) * 128;   // k += 32 floats
            const char* ak1 = asrc1 + (size_t)(kb + 1) * 128;
            GLL16(ak0, adst + nxt);
            GLL16(ak1, adst + nxt + 8192);
        }
        // a fragment: contiguous 32 B per lane, conflict-free
        f32x4 alo = *reinterpret_cast<const f32x4*>(smem + abase + cur);
        f32x4 ahi = *reinterpret_cast<const f32x4*>(smem + abase + cur + 16);
        f16x8 t;
#pragma unroll
        for (int j = 0; j < 4; ++j) { t[j] = (_Float16)alo[j]; t[j + 4] = (_Float16)ahi[j]; }
        const f16x8* wb = reinterpret_cast<const f16x8*>(smem + cur) + lane;
#pragma unroll
        for (int g = 0; g < 4; ++g) {
            f16x8 w0 = wb[(g * 4 + 0) * 64];
            f16x8 w1 = wb[(g * 4 + 1) * 64];
            f16x8 w2 = wb[(g * 4 + 2) * 64];
            f16x8 w3 = wb[(g * 4 + 3) * 64];
            acc[g * 4 + 0] = __builtin_amdgcn_mfma_f32_16x16x32_f16(w0, t, acc[g * 4 + 0], 0, 0, 0);
            acc[g * 4 + 1] = __builtin_amdgcn_mfma_f32_16x16x32_f16(w1, t, acc[g * 4 + 1], 0, 0, 0);
            acc[g * 4 + 2] = __builtin_amdgcn_mfma_f32_16x16x32_f16(w2, t, acc[g * 4 + 2], 0, 0, 0);
            acc[g * 4 + 3] = __builtin_amdgcn_mfma_f32_16x16x32_f16(w3, t, acc[g * 4 + 3], 0, 0, 0);
        }
        __syncthreads();   // sW/sa[cur] reads done; stage(kb+1) drained
    }

    // ---- Ghost BN stats (DPP over 16 lanes, LDS combine) ----
    float* sSum = (float*)smem;               // [8][256]  (overlay on W buf 0)
    float* sSq  = (float*)(smem + 8192);
    float* sA   = (float*)(smem + 16384);
    float* sB   = (float*)(smem + 17408);
#pragma unroll
    for (int ct = 0; ct < 16; ++ct) {
        f32x4 s = acc[ct];
        f32x4 qv = s * s;
#pragma unroll
        for (int c = 0; c < 4; ++c) { s[c] = rsum16(s[c]); qv[c] = rsum16(qv[c]); }
        if (lrow == 0) {
            *reinterpret_cast<f32x4*>(&sSum[wid * D + ct * 16 + q * 4]) = s;
            *reinterpret_cast<f32x4*>(&sSq [wid * D + ct * 16 + q * 4]) = qv;
        }
    }
    __syncthreads();
    if (tid < D) {
        float s = 0.f, qq = 0.f;
#pragma unroll
        for (int w = 0; w < 8; ++w) { s += sSum[w * D + tid]; qq += sSq[w * D + tid]; }
        float mean = s * (1.0f / 128.0f);
        float var  = qq * (1.0f / 128.0f) - mean * mean;
        float g    = gamma[tid] * rsqrtf(var + BN_EPS);
        sA[tid] = g;
        sB[tid] = beta[tid] - mean * g;
    }
    __syncthreads();

    // ---- epilogue: BN apply, * priors, sparsemax (one row per lrow-lane) ----
    const float* pr = priors + (size_t)myrow * D;
    float m = -1e30f;
#pragma unroll
    for (int ct = 0; ct < 16; ++ct) {
        int c0 = ct * 16 + q * 4;
        f32x4 ga = *reinterpret_cast<const f32x4*>(&sA[c0]);
        f32x4 bb = *reinterpret_cast<const f32x4*>(&sB[c0]);
        f32x4 p  = *reinterpret_cast<const f32x4*>(pr + c0);
        f32x4 x  = (acc[ct] * ga + bb) * p;
        acc[ct] = x;
        m = fmaxf(m, fmaxf(fmaxf(x[0], x[1]), fmaxf(x[2], x[3])));
    }
    m = fmaxf(m, __shfl_xor(m, 16));
    m = fmaxf(m, __shfl_xor(m, 32));

    // Michelot fixed-point from tau0 = m-1 (monotone to the exact root).
    float tau = m - 1.0f;
#pragma unroll 1
    for (int it = 0; it < 32; ++it) {
        float s = 0.f, c = 0.f;
#pragma unroll
        for (int ct = 0; ct < 16; ++ct)
#pragma unroll
            for (int k = 0; k < 4; ++k) {
                float zz = acc[ct][k];
                if (zz > tau) { s += zz; c += 1.f; }
            }
        s += __shfl_xor(s, 16); c += __shfl_xor(c, 16);
        s += __shfl_xor(s, 32); c += __shfl_xor(c, 32);
        float n = (s - 1.0f) / c;
        bool done = (n <= tau);
        tau = fmaxf(tau, n);
        if (__all(done)) break;
    }

    float* ob = out + (size_t)myrow * D;
#pragma unroll
    for (int ct = 0; ct < 16; ++ct) {
        int c0 = ct * 16 + q * 4;
        f32x4 x = acc[ct];
        f32x4 r;
#pragma unroll
        for (int k = 0; k < 4; ++k) r[k] = fmaxf(x[k] - tau, 0.f);
        __builtin_nontemporal_store(r, reinterpret_cast<f32x4*>(&ob[c0]));
    }
}

extern "C" void kernel_launch(void* const* d_in, const int* in_sizes, int n_in,
                              void* d_out, int out_size, void* d_ws, size_t ws_size,
                              hipStream_t stream) {
    const float* a      = (const float*)d_in[0];
    const float* priors = (const float*)d_in[1];
    const float* W      = (const float*)d_in[2];
    // d_in[3] = b : unused — ghost-BN mean subtraction cancels any per-column bias.
    const float* gamma  = (const float*)d_in[4];
    const float* beta   = (const float*)d_in[5];
    float* out = (float*)d_out;
    _Float16* wp = (_Float16*)d_ws;   // 256*256 f16 = 128 KB packed W

    const int B = in_sizes[0] / D;        // 262144
    const int nchunks = B / VBS;          // 2048

    hipLaunchKernelGGL(pack_w_kernel, dim3(32), dim3(256), 0, stream, W, wp);
    hipLaunchKernelGGL(fused_kernel, dim3(nchunks), dim3(512), 0, stream,
                       a, priors, wp, gamma, beta, out);
}